// Round 3
// baseline (2627.631 us; speedup 1.0000x reference)
//
#include <hip/hip_runtime.h>
#include <stdint.h>

#define BB 16
#define EE 256
#define TT 4096
#define FF 512
#define RK 10
#define NIT 5

typedef __attribute__((ext_vector_type(8))) short short8;
typedef __attribute__((ext_vector_type(4))) float f32x4;

__device__ __forceinline__ unsigned short f2bf(float x){
  unsigned int u = __float_as_uint(x);
  unsigned int r = (u + 0x7FFFu + ((u >> 16) & 1u)) >> 16;
  return (unsigned short)r;
}
__device__ __forceinline__ float bf2f(unsigned short s){
  return __uint_as_float(((unsigned int)s) << 16);
}

// ---------------- setup kernels ----------------

__global__ void k_params(const float* lam_log, const float* mu_log,
                         const float* nu_log, const float* gl, float* prm){
  int k = threadIdx.x;
  if (k < NIT){
    float lam = expf(lam_log[k]);
    float mu  = expf(mu_log[k]);
    float nu  = expf(nu_log[k]);
    float gam = 1.0f/(1.0f+expf(-gl[k]));
    prm[k*8+0]=lam; prm[k*8+1]=mu; prm[k*8+2]=nu; prm[k*8+3]=gam; prm[k*8+4]=lam/nu;
  }
}

__global__ void k_initX(const float4* __restrict__ Y, const float4* __restrict__ Om,
                        float4* __restrict__ X){
  int i = blockIdx.x*256 + threadIdx.x;
  float4 y = Y[i], o = Om[i];
  X[i] = make_float4(y.x*o.x, y.y*o.y, y.z*o.z, y.w*o.w);
}

__global__ void k_qtrans(const float* __restrict__ Q0, float* __restrict__ Qt){
  int idx = blockIdx.x*256 + threadIdx.x;   // b*TT + t
  int b = idx >> 12, t = idx & (TT-1);
  #pragma unroll
  for (int j=0;j<RK;j++)
    Qt[((size_t)b*RK + j)*TT + t] = Q0[(size_t)idx*RK + j];
}

// R (b,E,F) fp32 -> bf16 copy (coalesced)
__global__ void k_rbf(const float4* __restrict__ Rm, ushort4* __restrict__ Rbf){
  int i = blockIdx.x*256 + threadIdx.x;
  float4 r = Rm[i];
  ushort4 o; o.x=f2bf(r.x); o.y=f2bf(r.y); o.z=f2bf(r.z); o.w=f2bf(r.w);
  Rbf[i] = o;
}

// R^T (b,F,E) bf16
__global__ void k_rtrans(const float* __restrict__ Rm, unsigned short* __restrict__ Rtbf){
  int f = blockIdx.x, b = blockIdx.y, e = threadIdx.x;
  Rtbf[((size_t)b*FF + f)*EE + e] = f2bf(Rm[((size_t)b*EE + e)*FF + f]);
}

// A_scale = (R*R)^T @ (Om*Om) as uint8 (counts; clamp 255); XCD-swizzled 1D grid
__global__ void k_ascale(const unsigned short* __restrict__ Rtbf, const float* __restrict__ Om,
                         unsigned char* __restrict__ As){
  int id = blockIdx.x;
  int xcd = id & 7;
  int within = id >> 3;            // 0..4095
  int f = within & (FF-1);
  int g = ((within >> 9) << 3) + xcd;  // 0..63
  int b = g >> 2;
  int t = (g & 3)*1024 + threadIdx.x*4;
  __shared__ int s_cnt;
  __shared__ short s_idx[EE];
  if (threadIdx.x==0) s_cnt = 0;
  __syncthreads();
  {
    int e = threadIdx.x;
    float w = bf2f(Rtbf[((size_t)b*FF + f)*EE + e]);
    if (w != 0.0f){ int p = atomicAdd(&s_cnt,1); s_idx[p]=(short)e; }
  }
  __syncthreads();
  int cnt = s_cnt;
  float4 acc = {0,0,0,0};
  const float* Ob = Om + (size_t)b*EE*TT + t;
  for (int it=0; it<cnt; ++it){
    int e = s_idx[it];
    float4 o = *(const float4*)(Ob + (size_t)e*TT);
    acc.x += o.x*o.x; acc.y += o.y*o.y; acc.z += o.z*o.z; acc.w += o.w*o.w;
  }
  uchar4 r;
  r.x = (unsigned char)fminf(acc.x, 255.f);
  r.y = (unsigned char)fminf(acc.y, 255.f);
  r.z = (unsigned char)fminf(acc.z, 255.f);
  r.w = (unsigned char)fminf(acc.w, 255.f);
  *(uchar4*)(As + ((size_t)b*FF + f)*TT + t) = r;
}

// ---------------- per-iteration small kernels ----------------

__global__ void k_lhsQ(const float* __restrict__ Qt, const float* __restrict__ prm,
                       float* __restrict__ lhs, int k){
  int p = blockIdx.x, b = blockIdx.y;
  int i = 0, rem = p;
  while (rem >= i+1){ rem -= (i+1); ++i; }
  int j = rem;
  const float* qi = Qt + ((size_t)b*RK + i)*TT;
  const float* qj = Qt + ((size_t)b*RK + j)*TT;
  float a = 0.0f;
  for (int t = threadIdx.x*4; t < TT; t += 1024){
    float4 x = *(const float4*)(qi+t);
    float4 y = *(const float4*)(qj+t);
    a += x.x*y.x + x.y*y.y + x.z*y.z + x.w*y.w;
  }
  __shared__ float red[256];
  red[threadIdx.x] = a; __syncthreads();
  for (int s=128; s>0; s>>=1){
    if (threadIdx.x < s) red[threadIdx.x] += red[threadIdx.x+s];
    __syncthreads();
  }
  if (threadIdx.x==0){
    float v = red[0];
    if (i==j) v += prm[k*8+4];
    lhs[(b*RK+i)*RK + j] = v;
    lhs[(b*RK+j)*RK + i] = v;
  }
}

__global__ void k_lhsP(const float* __restrict__ P, const float* __restrict__ prm,
                       float* __restrict__ lhs, int k){
  int p = blockIdx.x, b = blockIdx.y;
  int i = 0, rem = p;
  while (rem >= i+1){ rem -= (i+1); ++i; }
  int j = rem;
  int e = threadIdx.x;
  const float* pr = P + ((size_t)b*EE + e)*RK;
  float a = pr[i]*pr[j];
  __shared__ float red[256];
  red[threadIdx.x] = a; __syncthreads();
  for (int s=128; s>0; s>>=1){
    if (threadIdx.x < s) red[threadIdx.x] += red[threadIdx.x+s];
    __syncthreads();
  }
  if (threadIdx.x==0){
    float v = red[0];
    if (i==j) v += prm[k*8+4];
    lhs[(b*RK+i)*RK + j] = v;
    lhs[(b*RK+j)*RK + i] = v;
  }
}

__global__ void k_invert(const float* __restrict__ lhs, float* __restrict__ inv){
  int b = blockIdx.x;
  __shared__ float aug[RK][2*RK];
  int tid = threadIdx.x;
  int i = tid / (2*RK), j = tid % (2*RK);
  bool act = tid < RK*2*RK;
  if (act) aug[i][j] = (j < RK) ? lhs[(b*RK+i)*RK + j] : ((j-RK)==i ? 1.0f : 0.0f);
  __syncthreads();
  for (int kk=0; kk<RK; ++kk){
    float pinv = 1.0f / aug[kk][kk];
    __syncthreads();
    if (act && i==kk) aug[i][j] *= pinv;
    __syncthreads();
    float factor = (act && i!=kk) ? aug[i][kk] : 0.0f;
    float pivrow = act ? aug[kk][j] : 0.0f;
    __syncthreads();
    if (act && i!=kk) aug[i][j] -= factor * pivrow;
    __syncthreads();
  }
  if (act && j >= RK) inv[(b*RK+i)*RK + (j-RK)] = aug[i][j];
}

__global__ void k_Pupd(const float* __restrict__ X, const float* __restrict__ Qt,
                       const float* __restrict__ inv, float* __restrict__ P){
  int e = blockIdx.x, b = blockIdx.y;
  const float* xr = X + ((size_t)b*EE + e)*TT;
  const float* qb = Qt + (size_t)b*RK*TT;
  float acc[RK];
  #pragma unroll
  for (int j=0;j<RK;j++) acc[j]=0.0f;
  for (int t = threadIdx.x*4; t < TT; t += 1024){
    float4 x = *(const float4*)(xr+t);
    #pragma unroll
    for (int j=0;j<RK;j++){
      float4 q = *(const float4*)(qb + (size_t)j*TT + t);
      acc[j] += x.x*q.x + x.y*q.y + x.z*q.z + x.w*q.w;
    }
  }
  __shared__ float partial[4][RK];
  int lane = threadIdx.x & 63, wv = threadIdx.x >> 6;
  #pragma unroll
  for (int j=0;j<RK;j++){
    float v = acc[j];
    for (int s=32;s>0;s>>=1) v += __shfl_down(v, s, 64);
    if (lane==0) partial[wv][j] = v;
  }
  __syncthreads();
  if (threadIdx.x < RK){
    int i = threadIdx.x;
    float out = 0.0f;
    #pragma unroll
    for (int j=0;j<RK;j++){
      float xq = partial[0][j]+partial[1][j]+partial[2][j]+partial[3][j];
      out += xq * inv[(b*RK+j)*RK + i];
    }
    P[((size_t)b*EE + e)*RK + i] = out;
  }
}

__global__ void k_Qupd(const float* __restrict__ X, const float* __restrict__ P,
                       const float* __restrict__ inv, float* __restrict__ Qt){
  int b = blockIdx.y;
  int t = blockIdx.x*256 + threadIdx.x;
  __shared__ float sP[EE*RK];
  __shared__ float sInv[RK*RK];
  for (int i=threadIdx.x; i<EE*RK; i+=256) sP[i] = P[(size_t)b*EE*RK + i];
  if (threadIdx.x < RK*RK) sInv[threadIdx.x] = inv[b*RK*RK + threadIdx.x];
  __syncthreads();
  float acc[RK];
  #pragma unroll
  for (int j=0;j<RK;j++) acc[j]=0.0f;
  const float* xb = X + (size_t)b*EE*TT + t;
  for (int e=0;e<EE;e++){
    float x = xb[(size_t)e*TT];
    #pragma unroll
    for (int j=0;j<RK;j++) acc[j] += x * sP[e*RK+j];
  }
  #pragma unroll
  for (int i=0;i<RK;i++){
    float q = 0.0f;
    #pragma unroll
    for (int j=0;j<RK;j++) q += acc[j]*sInv[j*RK+i];
    Qt[((size_t)b*RK + i)*TT + t] = q;
  }
}

// ---------------- MFMA GEMM + fused epilogues ----------------
// MODE 1: C = Rbf(b,E,F) @ A  with V = AbfT (b,T,F);  epilogue: X + resid_T(b,T,E)
// MODE 2: C = Rtbf(b,F,E) @ resid with V = residT (b,T,E); epilogue: A update + AbfT(b,T,F)
// Tile 128x128, BK=64, 4 waves (2x2), 16 mfma_f32_16x16x32_bf16 subtiles/wave.
template<int MODE>
__global__ __launch_bounds__(256) void k_mfma(
    const unsigned short* __restrict__ Wg,
    const unsigned short* __restrict__ Vg,
    const float* __restrict__ Y, const float* __restrict__ Om,
    const float* __restrict__ Qt, const float* __restrict__ Pg,
    const unsigned char* __restrict__ Asu, float* __restrict__ Adev,
    float* __restrict__ Xo, unsigned short* __restrict__ Tout,
    const float* __restrict__ prm, int kit)
{
  constexpr int M   = (MODE==1)? EE : FF;
  constexpr int K   = (MODE==1)? FF : EE;
  constexpr int NKT = K/64;
  constexpr int RSO = (MODE==1)? EE : FF;   // Tout row stride

  __shared__ char smem[40960];
  short* sW = (short*)smem;              // 128 x 72 shorts
  short* sV = (short*)(smem + 18432);    // 128 x 72 shorts

  int tid = threadIdx.x;
  int lane = tid & 63;
  int wid = tid >> 6;
  int l15 = lane & 15, quad = lane >> 4;
  int wm = wid & 1, wn = wid >> 1;

  int id = blockIdx.x;
  constexpr int MT = M/128;
  int mt = id % MT; int rest = id / MT;
  int nt = rest & 31; int b = rest >> 5;
  int m_blk = mt*128, t_blk = nt*128;

  const unsigned short* Wb = Wg + (size_t)b*M*K + (size_t)m_blk*K;
  const unsigned short* Vb = Vg + (size_t)b*TT*K + (size_t)t_blk*K;

  f32x4 acc[4][4];
  #pragma unroll
  for (int i=0;i<4;i++)
    #pragma unroll
    for (int j=0;j<4;j++) acc[i][j] = (f32x4){0.f,0.f,0.f,0.f};

  int srow = tid >> 3, sc = tid & 7;   // staging: per pass, row = l*32+srow, chunk sc

  for (int kt=0; kt<NKT; ++kt){
    int k0 = kt*64;
    short8 gw[4], gv[4];
    #pragma unroll
    for (int l=0;l<4;l++){
      gw[l] = *(const short8*)(Wb + (size_t)(l*32+srow)*K + k0 + sc*8);
      gv[l] = *(const short8*)(Vb + (size_t)(l*32+srow)*K + k0 + sc*8);
    }
    __syncthreads();
    #pragma unroll
    for (int l=0;l<4;l++){
      *(short8*)&sW[(l*32+srow)*72 + sc*8] = gw[l];
      *(short8*)&sV[(l*32+srow)*72 + sc*8] = gv[l];
    }
    __syncthreads();
    #pragma unroll
    for (int s=0;s<2;s++){
      short8 af[4], bfv[4];
      int c = s*4 + quad;
      #pragma unroll
      for (int mi=0;mi<4;mi++) af[mi]  = *(const short8*)&sW[(wm*64+mi*16+l15)*72 + c*8];
      #pragma unroll
      for (int ni=0;ni<4;ni++) bfv[ni] = *(const short8*)&sV[(wn*64+ni*16+l15)*72 + c*8];
      #pragma unroll
      for (int mi=0;mi<4;mi++)
        #pragma unroll
        for (int ni=0;ni<4;ni++)
          acc[mi][ni] = __builtin_amdgcn_mfma_f32_16x16x32_bf16(af[mi], bfv[ni], acc[mi][ni], 0,0,0);
    }
  }
  __syncthreads();

  if (MODE==1){
    // load P-tile (128x10) and Q-tile (10x128) into LDS
    float* sPf = (float*)smem;            // 1280 floats
    float* sQf = (float*)(smem + 5120);   // 1280 floats
    for (int i=tid; i<1280; i+=256)
      sPf[i] = Pg[((size_t)b*EE + m_blk + i/10)*RK + (i%10)];
    for (int i=tid; i<1280; i+=256){
      int j = i>>7, t = i&127;
      sQf[i] = Qt[((size_t)b*RK + j)*TT + t_blk + t];
    }
    __syncthreads();
    float nu = prm[kit*8+2];
    short* sT = (short*)(smem + 10240) + wid*(16*68);
    for (int ni=0; ni<4; ++ni){
      int t_l = wn*64 + ni*16 + l15;
      size_t tg = (size_t)(t_blk + t_l);
      #pragma unroll
      for (int mi=0; mi<4; ++mi){
        #pragma unroll
        for (int rg=0; rg<4; ++rg){
          int e_lw = mi*16 + quad*4 + rg;
          int e_l  = wm*64 + e_lw;
          size_t off = ((size_t)b*EE + m_blk + e_l)*TT + tg;
          float ra = acc[mi][ni][rg];
          float y = Y[off], om = Om[off];
          float pq = 0.f;
          #pragma unroll
          for (int j=0;j<RK;j++) pq += sPf[e_l*RK+j] * sQf[(j<<7) + t_l];
          float d = y - ra;
          float x = (om*d + nu*pq) / (om + nu);   // om binary: om^2 == om
          Xo[off] = x;
          sT[l15*68 + e_lw] = (short)f2bf(om*(d - x));
        }
      }
      __syncthreads();
      #pragma unroll
      for (int i2=0;i2<4;i2++){
        int row = i2*4 + quad;
        ushort4 v = *(const ushort4*)&((unsigned short*)sT)[row*68 + l15*4];
        *(ushort4*)&Tout[((size_t)b*TT + t_blk + wn*64 + ni*16 + row)*RSO + m_blk + wm*64 + l15*4] = v;
      }
      __syncthreads();
    }
  } else {
    float muv = prm[kit*8+1], gam = prm[kit*8+3];
    short* sT = (short*)smem + wid*(16*68);
    for (int ni=0; ni<4; ++ni){
      int t_l = wn*64 + ni*16 + l15;
      size_t tg = (size_t)(t_blk + t_l);
      #pragma unroll
      for (int mi=0; mi<4; ++mi){
        #pragma unroll
        for (int rg=0; rg<4; ++rg){
          int f_lw = mi*16 + quad*4 + rg;
          int f_l  = wm*64 + f_lw;
          size_t off = ((size_t)b*FF + m_blk + f_l)*TT + tg;
          float g = acc[mi][ni][rg];
          float cnt = (float)Asu[off];
          float a_old = Adev[off];
          bool no = (cnt == 0.f);
          float rs = 1.f/(no ? 1.f : cnt);
          float ba = a_old + g*rs;
          float ad = copysignf(fmaxf(fabsf(ba) - muv*rs, 0.f), ba);
          if (no) ad = 0.f;
          float an = a_old + gam*(ad - a_old);
          Adev[off] = an;
          sT[l15*68 + f_lw] = (short)f2bf(an);
        }
      }
      __syncthreads();
      #pragma unroll
      for (int i2=0;i2<4;i2++){
        int row = i2*4 + quad;
        ushort4 v = *(const ushort4*)&((unsigned short*)sT)[row*68 + l15*4];
        *(ushort4*)&Tout[((size_t)b*TT + t_blk + wn*64 + ni*16 + row)*RSO + m_blk + wm*64 + l15*4] = v;
      }
      __syncthreads();
    }
  }
}

// ---------------- launch ----------------

extern "C" void kernel_launch(void* const* d_in, const int* in_sizes, int n_in,
                              void* d_out, int out_size, void* d_ws, size_t ws_size,
                              hipStream_t stream){
  const float* Y   = (const float*)d_in[0];
  const float* Rm  = (const float*)d_in[1];
  const float* Om  = (const float*)d_in[2];
  const float* P0  = (const float*)d_in[3];
  const float* Q0  = (const float*)d_in[4];
  const float* lam = (const float*)d_in[5];
  const float* mu  = (const float*)d_in[6];
  const float* nu  = (const float*)d_in[7];
  const float* gl  = (const float*)d_in[8];
  float* A = (float*)d_out;

  char* ws = (char*)d_ws;
  const size_t X_OFF    = 0;                                    // fp32 X  (67108864)
  const size_t REST_OFF = X_OFF    + (size_t)BB*EE*TT*4;        // resid_T bf16 (b,T,E) 33554432
  const size_t ABT_OFF  = REST_OFF + (size_t)BB*TT*EE*2;        // A^T bf16 (b,T,F) 67108864
  const size_t AS_OFF   = ABT_OFF  + (size_t)BB*TT*FF*2;        // A_scale u8 (b,F,T) 33554432
  const size_t RBF_OFF  = AS_OFF   + (size_t)BB*FF*TT*1;        // R bf16 (b,E,F) 4194304
  const size_t RTB_OFF  = RBF_OFF  + (size_t)BB*EE*FF*2;        // R^T bf16 (b,F,E) 4194304
  const size_t QT_OFF   = RTB_OFF  + (size_t)BB*FF*EE*2;        // Qt fp32 (b,10,T) 2621440
  const size_t P_OFF    = QT_OFF   + (size_t)BB*RK*TT*4;        // P fp32 163840
  const size_t LHS_OFF  = P_OFF    + (size_t)BB*EE*RK*4;
  const size_t INV_OFF  = LHS_OFF  + (size_t)BB*RK*RK*4;
  const size_t PRM_OFF  = INV_OFF  + (size_t)BB*RK*RK*4;

  float* X    = (float*)(ws + X_OFF);
  unsigned short* residT = (unsigned short*)(ws + REST_OFF);
  unsigned short* AbfT   = (unsigned short*)(ws + ABT_OFF);
  unsigned char*  As     = (unsigned char*)(ws + AS_OFF);
  unsigned short* Rbf    = (unsigned short*)(ws + RBF_OFF);
  unsigned short* Rtbf   = (unsigned short*)(ws + RTB_OFF);
  float* Qt   = (float*)(ws + QT_OFF);
  float* P    = (float*)(ws + P_OFF);
  float* lhs  = (float*)(ws + LHS_OFF);
  float* inv  = (float*)(ws + INV_OFF);
  float* prm  = (float*)(ws + PRM_OFF);

  (void)P0; (void)in_sizes; (void)n_in; (void)ws_size;

  hipMemsetAsync(d_out, 0, (size_t)out_size*sizeof(float), stream);
  hipMemsetAsync(ws + ABT_OFF, 0, (size_t)BB*TT*FF*2, stream);
  k_params<<<1, 64, 0, stream>>>(lam, mu, nu, gl, prm);
  k_initX<<<BB*EE*TT/4/256, 256, 0, stream>>>((const float4*)Y, (const float4*)Om, (float4*)X);
  k_qtrans<<<BB*TT/256, 256, 0, stream>>>(Q0, Qt);
  k_rbf<<<BB*EE*FF/4/256, 256, 0, stream>>>((const float4*)Rm, (ushort4*)Rbf);
  k_rtrans<<<dim3(FF, BB), 256, 0, stream>>>(Rm, Rtbf);
  k_ascale<<<FF*4*BB, 256, 0, stream>>>(Rtbf, Om, As);

  for (int k=0; k<NIT; ++k){
    k_lhsQ  <<<dim3(55, BB), 256, 0, stream>>>(Qt, prm, lhs, k);
    k_invert<<<BB, 256, 0, stream>>>(lhs, inv);
    k_Pupd  <<<dim3(EE, BB), 256, 0, stream>>>(X, Qt, inv, P);
    k_lhsP  <<<dim3(55, BB), 256, 0, stream>>>(P, prm, lhs, k);
    k_invert<<<BB, 256, 0, stream>>>(lhs, inv);
    k_Qupd  <<<dim3(TT/256, BB), 256, 0, stream>>>(X, P, inv, Qt);
    k_mfma<1><<<(EE/128)*32*BB, 256, 0, stream>>>(Rbf, AbfT, Y, Om, Qt, P,
                                                  nullptr, nullptr, X, residT, prm, k);
    k_mfma<2><<<(FF/128)*32*BB, 256, 0, stream>>>(Rtbf, residT, nullptr, nullptr, nullptr, nullptr,
                                                  As, A, nullptr, AbfT, prm, k);
  }
}